// Round 4
// baseline (128.900 us; speedup 1.0000x reference)
//
#include <hip/hip_runtime.h>
#include <hip/hip_bf16.h>

// N=2048, D_IN=128, H=256, D_EMB=64
// inputs: 0:x 1:adj(unused) 2:W0 3:b0 4:W1 5:b1 6:W2 7:b2 8:temp 9:theta
// d_out: out[2048*128] then adj_wts[2048*2048]
//
// R16: k2 occupancy attack. R14's one direct k2f profile: Occupancy 25%
// (1024 blocks = 4 blocks/CU), all-idle counters -> latency-bound. Now:
// 128-col j-strips, grid (128,16) = 2048 blocks = 8 blocks/CU, LDS halved
// (single P tile), __launch_bounds__(256,8). 16 partials -> k3<16>.
// adjw stores nontemporal (pure streaming output, keep L2 for reuse data).
// k0/k1 unchanged from proven R15. Fallback path = old 8-strip + scalar k1.

typedef short bf16x8 __attribute__((ext_vector_type(8)));
typedef float f32x4 __attribute__((ext_vector_type(4)));

__device__ __forceinline__ unsigned short f2bf(float f) {
    unsigned u = __float_as_uint(f);
    unsigned r = u + 0x7fffu + ((u >> 16) & 1u);
    return (unsigned short)(r >> 16);
}

// round-half-up to bf16 — matches pack_rne8's per-element op exactly
__device__ __forceinline__ unsigned short f2bf_hu(float f) {
    return (unsigned short)((__float_as_uint(f) + 0x8000u) >> 16);
}

// pack 8 f32 -> bf16x8 with round-half-up
__device__ __forceinline__ bf16x8 pack_rne8(const float* p) {
    union { unsigned u[4]; bf16x8 v; } r;
    #pragma unroll
    for (int i = 0; i < 4; ++i) {
        unsigned lo = __float_as_uint(p[2 * i]) + 0x8000u;
        unsigned hi = __float_as_uint(p[2 * i + 1]) + 0x8000u;
        r.u[i] = __builtin_amdgcn_perm(hi, lo, 0x07060302u);
    }
    return r.v;
}

// truncation-pack (for the already-rounded P tile in k2)
__device__ __forceinline__ bf16x8 pack_bf8(const float* p) {
    union { unsigned u[4]; bf16x8 v; } r;
    #pragma unroll
    for (int i = 0; i < 4; ++i)
        r.u[i] = __builtin_amdgcn_perm(__float_as_uint(p[2 * i + 1]),
                                       __float_as_uint(p[2 * i]), 0x07060302u);
    return r.v;
}

// ---------------- Kernel 0: weight transpose + bf16 convert ----------------
__global__ __launch_bounds__(256) void k0_prep(
    const float* __restrict__ W0, const float* __restrict__ W1,
    const float* __restrict__ W2,
    unsigned short* __restrict__ W0T,
    unsigned short* __restrict__ W1T,
    unsigned short* __restrict__ W2T)
{
    const int gid = blockIdx.x * 256 + threadIdx.x;   // 0..32767
    {   // W0T: h = gid>>7, k = gid&127
        const int h = gid >> 7, k = gid & 127;
        W0T[gid] = f2bf_hu(W0[(size_t)k * 256 + h]);
    }
    if (gid < 16384) {   // W1T: h = gid>>8, k = gid&255
        const int h = gid >> 8, k = gid & 255;
        W1T[gid] = f2bf_hu(W1[(size_t)k * 64 + h]);
    } else {             // W2T: c = o>>7, k = o&127
        const int o = gid - 16384;
        const int c = o >> 7, k = o & 127;
        W2T[o] = f2bf_hu(W2[(size_t)k * 128 + c]);
    }
}

// ---------------- Kernel 1: fused MLP via MFMA, 256 blocks x 4 waves ----------------
// block = (i-tile = bid>>1, role = bid&1).
// role 0: GEMM0 (x@W0, 16x256) -> LDS -> GEMM1 (emb) + sq.
// role 1: GEMM2 (x@W2) only — no LDS, no barrier.
template<int VEC>
__global__ __launch_bounds__(256, 2) void k1_mfma(
    const float* __restrict__ x,
    const float* __restrict__ W0, const float* __restrict__ b0,
    const float* __restrict__ W1, const float* __restrict__ b1,
    const float* __restrict__ W2, const float* __restrict__ b2,
    const unsigned short* __restrict__ W0T,
    const unsigned short* __restrict__ W1T,
    const unsigned short* __restrict__ W2T,
    unsigned short* __restrict__ emb_bf,   // [2048][64] bf16
    unsigned short* __restrict__ xlT_bf,   // [128][2048] bf16
    float* __restrict__ sq)                // [2048]
{
    constexpr int LDO = 264;               // out_x LDS stride (bf16 elems)
    __shared__ unsigned short oxb[16 * LDO];
    __shared__ float sqs[4][16];

    const int t = threadIdx.x;
    const int lane = t & 63;
    const int w = t >> 6;      // wave 0..3
    const int m = lane & 15;
    const int q = lane >> 4;
    const int tile = blockIdx.x >> 1;
    const int role = blockIdx.x & 1;
    const int i0 = tile * 16;

    // A-fragments of x (rows i0+m, K=128) — needed by both roles
    bf16x8 ax[4];
    #pragma unroll
    for (int kb = 0; kb < 4; ++kb) {
        float xf[8];
        *(f32x4*)&xf[0] = *(const f32x4*)(x + (size_t)(i0 + m) * 128 + kb * 32 + q * 8);
        *(f32x4*)&xf[4] = *(const f32x4*)(x + (size_t)(i0 + m) * 128 + kb * 32 + q * 8 + 4);
        ax[kb] = pack_rne8(xf);
    }

    if (role == 0) {
        // prefetch W1 fragments (independent of GEMM0)
        const int h1 = w * 16 + m;
        const float bias1 = b1[h1];
        bf16x8 wp[8];
        #pragma unroll
        for (int kb = 0; kb < 8; ++kb) {
            if (VEC) {
                wp[kb] = *(const bf16x8*)(W1T + (size_t)h1 * 256 + kb * 32 + q * 8);
            } else {
                float wf[8];
                #pragma unroll
                for (int j = 0; j < 8; ++j) wf[j] = W1[(size_t)(kb * 32 + q * 8 + j) * 64 + h1];
                wp[kb] = pack_rne8(wf);
            }
        }

        // GEMM0: out_x = relu(x @ W0 + b0); wave w covers cols w*64..w*64+63
        #pragma unroll
        for (int hh = 0; hh < 4; ++hh) {
            const int h = (w * 4 + hh) * 16 + m;
            float bb = b0[h];
            f32x4 acc = {bb, bb, bb, bb};
            #pragma unroll
            for (int kb = 0; kb < 4; ++kb) {
                bf16x8 bfrag;
                if (VEC) {
                    bfrag = *(const bf16x8*)(W0T + (size_t)h * 128 + kb * 32 + q * 8);
                } else {
                    float wf[8];
                    #pragma unroll
                    for (int j = 0; j < 8; ++j) wf[j] = W0[(size_t)(kb * 32 + q * 8 + j) * 256 + h];
                    bfrag = pack_rne8(wf);
                }
                acc = __builtin_amdgcn_mfma_f32_16x16x32_bf16(ax[kb], bfrag, acc, 0, 0, 0);
            }
            #pragma unroll
            for (int r = 0; r < 4; ++r)
                oxb[(q * 4 + r) * LDO + h] = f2bf(fmaxf(acc[r], 0.0f));
        }
        __syncthreads();

        // GEMM1: emb = relu(out_x @ W1 + b1), wave w -> cols w*16..w*16+15
        f32x4 acc = {bias1, bias1, bias1, bias1};
        #pragma unroll
        for (int kb = 0; kb < 8; ++kb) {
            bf16x8 af = *(const bf16x8*)(&oxb[m * LDO + kb * 32 + q * 8]);
            acc = __builtin_amdgcn_mfma_f32_16x16x32_bf16(af, wp[kb], acc, 0, 0, 0);
        }
        float s2[4];
        #pragma unroll
        for (int r = 0; r < 4; ++r) {
            float e = fmaxf(acc[r], 0.0f);
            emb_bf[(size_t)(i0 + q * 4 + r) * 64 + h1] = f2bf(e);
            s2[r] = e * e;
        }
        #pragma unroll
        for (int r = 0; r < 4; ++r) {
            float v = s2[r];
            v += __shfl_xor(v, 1);
            v += __shfl_xor(v, 2);
            v += __shfl_xor(v, 4);
            v += __shfl_xor(v, 8);
            if (m == 0) sqs[w][q * 4 + r] = v;
        }
        __syncthreads();
        if (t < 16)
            sq[i0 + t] = sqs[0][t] + sqs[1][t] + sqs[2][t] + sqs[3][t];
    } else {
        // GEMM2: x_last = x @ W2 + b2, wave w -> cols w*32..w*32+31
        bf16x8 wp[8];
        #pragma unroll
        for (int hh = 0; hh < 2; ++hh) {
            const int c = (w * 2 + hh) * 16 + m;
            #pragma unroll
            for (int kb = 0; kb < 4; ++kb) {
                if (VEC) {
                    wp[hh * 4 + kb] = *(const bf16x8*)(W2T + (size_t)c * 128 + kb * 32 + q * 8);
                } else {
                    float wf[8];
                    #pragma unroll
                    for (int j = 0; j < 8; ++j) wf[j] = W2[(size_t)(kb * 32 + q * 8 + j) * 128 + c];
                    wp[hh * 4 + kb] = pack_rne8(wf);
                }
            }
        }
        #pragma unroll
        for (int hh = 0; hh < 2; ++hh) {
            const int c = (w * 2 + hh) * 16 + m;
            float bb = b2[c];
            f32x4 acc = {bb, bb, bb, bb};
            #pragma unroll
            for (int kb = 0; kb < 4; ++kb)
                acc = __builtin_amdgcn_mfma_f32_16x16x32_bf16(ax[kb], wp[hh * 4 + kb], acc, 0, 0, 0);
            uint2 pk;
            pk.x = (unsigned)f2bf(acc[0]) | ((unsigned)f2bf(acc[1]) << 16);
            pk.y = (unsigned)f2bf(acc[2]) | ((unsigned)f2bf(acc[3]) << 16);
            *(uint2*)(&xlT_bf[(size_t)c * 2048 + i0 + q * 4]) = pk;
        }
    }
}

// ---------------- Kernel 2: fused adjacency + A@x_last (partial stores) ----------------
// grid (128 i-tiles, 16/JT j-strips) x 256 thr. Strip = JT*128 cols.
// JT=1: 2048 blocks = 8/CU (occupancy play). NO fences, NO atomics.
template<int JT>
__global__ __launch_bounds__(256, 8) void k2f(
    const unsigned short* __restrict__ emb_bf,
    const unsigned short* __restrict__ xlT_bf,
    const float* __restrict__ sq,
    const float* __restrict__ tempp, const float* __restrict__ thetap,
    float* __restrict__ adjw,      // [2048][2048] f32
    float* __restrict__ outPart,   // [16/JT][128][1024] float2
    float* __restrict__ degPart)   // [16/JT][2048]
{
    constexpr int LDP = 132;
    __shared__ float Pt[JT][16 * LDP];
    __shared__ float degS[4][16];

    const int t = threadIdx.x;
    const int lane = t & 63;
    const int w = t >> 6;
    const int m = lane & 15;
    const int q = lane >> 4;
    const int i0 = blockIdx.x * 16;
    const int bj = blockIdx.y;
    const float scale = 1.0f + tempp[0];
    const float bias = 5.0f + thetap[0];

    bf16x8 a0 = *(const bf16x8*)(emb_bf + (size_t)(i0 + m) * 64 + q * 8);
    bf16x8 a1 = *(const bf16x8*)(emb_bf + (size_t)(i0 + m) * 64 + 32 + q * 8);
    float sqIr[4];
    #pragma unroll
    for (int r = 0; r < 4; ++r) sqIr[r] = sq[i0 + q * 4 + r];

    f32x4 accO0 = {0.f, 0.f, 0.f, 0.f};
    f32x4 accO1 = {0.f, 0.f, 0.f, 0.f};
    float dega[4] = {0.f, 0.f, 0.f, 0.f};
    const int cg = w * 32;

    #pragma unroll
    for (int jt = 0; jt < JT; ++jt) {
        const int j0 = (bj * JT + jt) * 128;
        float* P = &Pt[jt][0];

        // prefetch AX B-fragments (xlT) — independent of the P tile
        bf16x8 xb[8];
        #pragma unroll
        for (int s = 0; s < 4; ++s) {
            const int k = j0 + s * 32 + q * 8;
            xb[2 * s]     = *(const bf16x8*)(xlT_bf + (size_t)(cg + m) * 2048 + k);
            xb[2 * s + 1] = *(const bf16x8*)(xlT_bf + (size_t)(cg + 16 + m) * 2048 + k);
        }

        // S phase: wave w computes cols 32w..32w+31
        #pragma unroll
        for (int s = 0; s < 2; ++s) {
            const int col = (w * 2 + s) * 16 + m;
            const unsigned short* ebj = emb_bf + (size_t)(j0 + col) * 64;
            bf16x8 b0 = *(const bf16x8*)(ebj + q * 8);
            bf16x8 b1 = *(const bf16x8*)(ebj + 32 + q * 8);
            f32x4 S = {0.f, 0.f, 0.f, 0.f};
            S = __builtin_amdgcn_mfma_f32_16x16x32_bf16(a0, b0, S, 0, 0, 0);
            S = __builtin_amdgcn_mfma_f32_16x16x32_bf16(a1, b1, S, 0, 0, 0);

            const float csqJ = sq[j0 + col];
            const int gcol = j0 + col;
            #pragma unroll
            for (int r = 0; r < 4; ++r) {
                int grow = i0 + q * 4 + r;
                float dist = 2.0f * S[r] - sqIr[r] - csqJ;
                float z = scale * dist + bias;
                float p = __builtin_amdgcn_rcpf(1.0f + __expf(-z));
                if (grow == gcol) p += 1.0f;
                dega[r] += p;
                P[(q * 4 + r) * LDP + col] = p;
            }
        }
        __syncthreads();

        // adjw store: 32 consecutive lanes x 16B = 512B contiguous per
        // instruction -> 4 FULL 128B lines per instr. Nontemporal: pure
        // streaming output, keep L2 for emb/xlT/outPart reuse.
        {
            int row = t >> 5;            // 0..7
            int c0 = (t & 31) * 4;       // f32 col 0..124
            f32x4 v0 = *(const f32x4*)(&P[row * LDP + c0]);
            f32x4 v1 = *(const f32x4*)(&P[(row + 8) * LDP + c0]);
            __builtin_nontemporal_store(v0, (f32x4*)(adjw + (size_t)(i0 + row) * 2048 + j0 + c0));
            __builtin_nontemporal_store(v1, (f32x4*)(adjw + (size_t)(i0 + row + 8) * 2048 + j0 + c0));
        }

        // AX: acc += P(16x128) @ xlT (prefetched), K=128
        #pragma unroll
        for (int s = 0; s < 4; ++s) {
            float af[8];
            *(f32x4*)(&af[0]) = *(const f32x4*)(&P[m * LDP + s * 32 + q * 8]);
            *(f32x4*)(&af[4]) = *(const f32x4*)(&P[m * LDP + s * 32 + q * 8 + 4]);
            bf16x8 aa = pack_bf8(af);
            accO0 = __builtin_amdgcn_mfma_f32_16x16x32_bf16(aa, xb[2 * s], accO0, 0, 0, 0);
            accO1 = __builtin_amdgcn_mfma_f32_16x16x32_bf16(aa, xb[2 * s + 1], accO1, 0, 0, 0);
        }
        if (JT > 1 && jt + 1 < JT) __syncthreads();
    }

    // deg partial: reduce over m-lanes, combine 4 waves via LDS, plain store
    #pragma unroll
    for (int r = 0; r < 4; ++r) {
        float v = dega[r];
        v += __shfl_xor(v, 1);
        v += __shfl_xor(v, 2);
        v += __shfl_xor(v, 4);
        v += __shfl_xor(v, 8);
        if (m == 0) degS[w][q * 4 + r] = v;
    }
    __syncthreads();
    if (t < 16)
        degPart[bj * 2048 + i0 + t] =
            degS[0][t] + degS[1][t] + degS[2][t] + degS[3][t];

    // out partial: float2-packed so each 16-lane group writes one FULL 128B
    // line per instruction. Layout per (strip, i-tile): [(rit*4+w)*16+m] float2.
    float2* opf2 = (float2*)outPart + ((size_t)bj * 128 + blockIdx.x) * 1024;
    #pragma unroll
    for (int r = 0; r < 4; ++r) {
        float2 pk;
        pk.x = accO0[r];
        pk.y = accO1[r];
        opf2[((q * 4 + r) * 4 + w) * 16 + m] = pk;
    }
}

// ---------------- Kernel 3: out = relu(sum_p outPart / sum_p degPart) ----------------
template<int NP>
__global__ __launch_bounds__(256) void k3_fin(
    const float* __restrict__ outPart, const float* __restrict__ degPart,
    float* __restrict__ out)
{
    int gid = blockIdx.x * 256 + threadIdx.x;  // 131072 = 2048 rows * 64 (w,m)
    int i = gid >> 6;
    int wm = gid & 63;
    int w = wm >> 4, m = wm & 15;
    int tile = i >> 4, rit = i & 15;
    size_t base = (size_t)tile * 2048 + (size_t)((rit * 4 + w) * 16 + m) * 2;
    float s0 = 0.f, s1 = 0.f, d = 0.f;
    #pragma unroll
    for (int p = 0; p < NP; ++p) {
        const float* src = outPart + (size_t)p * 262144 + base;
        s0 += src[0];
        s1 += src[1];
        d += degPart[p * 2048 + i];
    }
    float dinv = 1.0f / d;
    out[(size_t)i * 128 + w * 32 + m] = fmaxf(s0 * dinv, 0.f);
    out[(size_t)i * 128 + w * 32 + 16 + m] = fmaxf(s1 * dinv, 0.f);
}

extern "C" void kernel_launch(void* const* d_in, const int* in_sizes, int n_in,
                              void* d_out, int out_size, void* d_ws, size_t ws_size,
                              hipStream_t stream) {
    (void)in_sizes; (void)n_in; (void)out_size;
    const float* x     = (const float*)d_in[0];
    const float* W0    = (const float*)d_in[2];
    const float* b0    = (const float*)d_in[3];
    const float* W1    = (const float*)d_in[4];
    const float* b1    = (const float*)d_in[5];
    const float* W2    = (const float*)d_in[6];
    const float* b2    = (const float*)d_in[7];
    const float* temp  = (const float*)d_in[8];
    const float* theta = (const float*)d_in[9];

    char* ws = (char*)d_ws;
    float* out  = (float*)d_out;              // [2048*128]
    float* adjw = (float*)d_out + 262144;     // [2048*2048]

    // Mode A (16-strip, vec weights) footprint:
    // emb 262144 | xlT 524288 | sq 8192 | degPart[16] 131072 | outPart 16 MiB
    // | W0T 65536 | W1T 32768 | W2T 32768  => 17833984 B total
    const bool big = (ws_size >= 17833984);

    if (big) {
        unsigned short* emb_bf = (unsigned short*)(ws);            // ->262144
        unsigned short* xlT_bf = (unsigned short*)(ws + 262144);   // ->786432
        float* sq      = (float*)(ws + 786432);                    // ->794624
        float* degPart = (float*)(ws + 794624);                    // ->925696
        float* outPart = (float*)(ws + 925696);                    // ->17702912
        unsigned short* W0T = (unsigned short*)(ws + 17702912);    // ->17768448
        unsigned short* W1T = (unsigned short*)(ws + 17768448);    // ->17801216
        unsigned short* W2T = (unsigned short*)(ws + 17801216);    // ->17833984

        k0_prep<<<128, 256, 0, stream>>>(W0, W1, W2, W0T, W1T, W2T);
        k1_mfma<1><<<256, 256, 0, stream>>>(x, W0, b0, W1, b1, W2, b2,
                                            W0T, W1T, W2T, emb_bf, xlT_bf, sq);
        k2f<1><<<dim3(128, 16), 256, 0, stream>>>(emb_bf, xlT_bf, sq, temp, theta,
                                                  adjw, outPart, degPart);
        k3_fin<16><<<512, 256, 0, stream>>>(outPart, degPart, out);
    } else {
        // fallback: proven R12-era 8-strip layout, scalar-gather k1
        unsigned short* emb_bf = (unsigned short*)(ws);            // ->262144
        unsigned short* xlT_bf = (unsigned short*)(ws + 262144);   // ->786432
        float* sq      = (float*)(ws + 786432);                    // ->794624
        float* degPart = (float*)(ws + 794624);                    // ->860160
        float* outPart = (float*)(ws + 860160);                    // ->9248768

        k1_mfma<0><<<256, 256, 0, stream>>>(x, W0, b0, W1, b1, W2, b2,
                                            nullptr, nullptr, nullptr,
                                            emb_bf, xlT_bf, sq);
        k2f<2><<<dim3(128, 8), 256, 0, stream>>>(emb_bf, xlT_bf, sq, temp, theta,
                                                 adjw, outPart, degPart);
        k3_fin<8><<<512, 256, 0, stream>>>(outPart, degPart, out);
    }
}

// Round 5
// 108.068 us; speedup vs baseline: 1.1928x; 1.1928x over previous
//
#include <hip/hip_runtime.h>
#include <hip/hip_bf16.h>

// N=2048, D_IN=128, H=256, D_EMB=64
// inputs: 0:x 1:adj(unused) 2:W0 3:b0 4:W1 5:b1 6:W2 7:b2 8:temp 9:theta
// d_out: out[2048*128] then adj_wts[2048*2048]
//
// R17: overhead-reduction direction (R16 taught: MORE blocks/partials = WORSE).
// (1) k0 dropped (R15: scalar k1 == vec k1 + k0) -> 3 launches.
// (2) k2 restructured: 256 blocks x 512 thr (8 waves), block = 16-row tile x
//     1024-col HALF of j-range (8 strips of 128, double-buffered P LDS,
//     1 barrier/strip = R12's proven pattern). Per-block prologue amortized
//     4x vs R15; partials per row: 8 -> 2. 16 waves/CU occupancy preserved.
// (3) k3 reads 2MB instead of 8.4MB, f32x4 both sides.

typedef short bf16x8 __attribute__((ext_vector_type(8)));
typedef float f32x4 __attribute__((ext_vector_type(4)));

__device__ __forceinline__ unsigned short f2bf(float f) {
    unsigned u = __float_as_uint(f);
    unsigned r = u + 0x7fffu + ((u >> 16) & 1u);
    return (unsigned short)(r >> 16);
}

// pack 8 f32 -> bf16x8 with round-half-up
__device__ __forceinline__ bf16x8 pack_rne8(const float* p) {
    union { unsigned u[4]; bf16x8 v; } r;
    #pragma unroll
    for (int i = 0; i < 4; ++i) {
        unsigned lo = __float_as_uint(p[2 * i]) + 0x8000u;
        unsigned hi = __float_as_uint(p[2 * i + 1]) + 0x8000u;
        r.u[i] = __builtin_amdgcn_perm(hi, lo, 0x07060302u);
    }
    return r.v;
}

// truncation-pack (for the already-rounded P tile in k2)
__device__ __forceinline__ bf16x8 pack_bf8(const float* p) {
    union { unsigned u[4]; bf16x8 v; } r;
    #pragma unroll
    for (int i = 0; i < 4; ++i)
        r.u[i] = __builtin_amdgcn_perm(__float_as_uint(p[2 * i + 1]),
                                       __float_as_uint(p[2 * i]), 0x07060302u);
    return r.v;
}

// ---------------- Kernel 1: fused MLP via MFMA, 256 blocks x 4 waves ----------------
// block = (i-tile = bid>>1, role = bid&1).
// role 0: GEMM0 (x@W0, 16x256) -> LDS -> GEMM1 (emb) + sq.
// role 1: GEMM2 (x@W2) only — no LDS, no barrier. (Proven R14/R15 path.)
__global__ __launch_bounds__(256, 2) void k1_mfma(
    const float* __restrict__ x,
    const float* __restrict__ W0, const float* __restrict__ b0,
    const float* __restrict__ W1, const float* __restrict__ b1,
    const float* __restrict__ W2, const float* __restrict__ b2,
    unsigned short* __restrict__ emb_bf,   // [2048][64] bf16
    unsigned short* __restrict__ xlT_bf,   // [128][2048] bf16
    float* __restrict__ sq)                // [2048]
{
    constexpr int LDO = 264;               // out_x LDS stride (bf16 elems)
    __shared__ unsigned short oxb[16 * LDO];
    __shared__ float sqs[4][16];

    const int t = threadIdx.x;
    const int lane = t & 63;
    const int w = t >> 6;      // wave 0..3
    const int m = lane & 15;
    const int q = lane >> 4;
    const int tile = blockIdx.x >> 1;
    const int role = blockIdx.x & 1;
    const int i0 = tile * 16;

    // A-fragments of x (rows i0+m, K=128) — needed by both roles
    bf16x8 ax[4];
    #pragma unroll
    for (int kb = 0; kb < 4; ++kb) {
        float xf[8];
        *(f32x4*)&xf[0] = *(const f32x4*)(x + (size_t)(i0 + m) * 128 + kb * 32 + q * 8);
        *(f32x4*)&xf[4] = *(const f32x4*)(x + (size_t)(i0 + m) * 128 + kb * 32 + q * 8 + 4);
        ax[kb] = pack_rne8(xf);
    }

    if (role == 0) {
        // prefetch W1 fragments (independent of GEMM0)
        const int h1 = w * 16 + m;
        const float bias1 = b1[h1];
        bf16x8 wp[8];
        #pragma unroll
        for (int kb = 0; kb < 8; ++kb) {
            float wf[8];
            #pragma unroll
            for (int j = 0; j < 8; ++j) wf[j] = W1[(size_t)(kb * 32 + q * 8 + j) * 64 + h1];
            wp[kb] = pack_rne8(wf);
        }

        // GEMM0: out_x = relu(x @ W0 + b0); wave w covers cols w*64..w*64+63
        #pragma unroll
        for (int hh = 0; hh < 4; ++hh) {
            const int h = (w * 4 + hh) * 16 + m;
            float bb = b0[h];
            f32x4 acc = {bb, bb, bb, bb};
            #pragma unroll
            for (int kb = 0; kb < 4; ++kb) {
                float wf[8];
                #pragma unroll
                for (int j = 0; j < 8; ++j) wf[j] = W0[(size_t)(kb * 32 + q * 8 + j) * 256 + h];
                acc = __builtin_amdgcn_mfma_f32_16x16x32_bf16(ax[kb], pack_rne8(wf), acc, 0, 0, 0);
            }
            #pragma unroll
            for (int r = 0; r < 4; ++r)
                oxb[(q * 4 + r) * LDO + h] = f2bf(fmaxf(acc[r], 0.0f));
        }
        __syncthreads();

        // GEMM1: emb = relu(out_x @ W1 + b1), wave w -> cols w*16..w*16+15
        f32x4 acc = {bias1, bias1, bias1, bias1};
        #pragma unroll
        for (int kb = 0; kb < 8; ++kb) {
            bf16x8 af = *(const bf16x8*)(&oxb[m * LDO + kb * 32 + q * 8]);
            acc = __builtin_amdgcn_mfma_f32_16x16x32_bf16(af, wp[kb], acc, 0, 0, 0);
        }
        float s2[4];
        #pragma unroll
        for (int r = 0; r < 4; ++r) {
            float e = fmaxf(acc[r], 0.0f);
            emb_bf[(size_t)(i0 + q * 4 + r) * 64 + h1] = f2bf(e);
            s2[r] = e * e;
        }
        #pragma unroll
        for (int r = 0; r < 4; ++r) {
            float v = s2[r];
            v += __shfl_xor(v, 1);
            v += __shfl_xor(v, 2);
            v += __shfl_xor(v, 4);
            v += __shfl_xor(v, 8);
            if (m == 0) sqs[w][q * 4 + r] = v;
        }
        __syncthreads();
        if (t < 16)
            sq[i0 + t] = sqs[0][t] + sqs[1][t] + sqs[2][t] + sqs[3][t];
    } else {
        // GEMM2: x_last = x @ W2 + b2, wave w -> cols w*32..w*32+31
        bf16x8 wp[8];
        #pragma unroll
        for (int hh = 0; hh < 2; ++hh) {
            const int c = (w * 2 + hh) * 16 + m;
            #pragma unroll
            for (int kb = 0; kb < 4; ++kb) {
                float wf[8];
                #pragma unroll
                for (int j = 0; j < 8; ++j) wf[j] = W2[(size_t)(kb * 32 + q * 8 + j) * 128 + c];
                wp[hh * 4 + kb] = pack_rne8(wf);
            }
        }
        #pragma unroll
        for (int hh = 0; hh < 2; ++hh) {
            const int c = (w * 2 + hh) * 16 + m;
            float bb = b2[c];
            f32x4 acc = {bb, bb, bb, bb};
            #pragma unroll
            for (int kb = 0; kb < 4; ++kb)
                acc = __builtin_amdgcn_mfma_f32_16x16x32_bf16(ax[kb], wp[hh * 4 + kb], acc, 0, 0, 0);
            uint2 pk;
            pk.x = (unsigned)f2bf(acc[0]) | ((unsigned)f2bf(acc[1]) << 16);
            pk.y = (unsigned)f2bf(acc[2]) | ((unsigned)f2bf(acc[3]) << 16);
            *(uint2*)(&xlT_bf[(size_t)c * 2048 + i0 + q * 4]) = pk;
        }
    }
}

// ---------------- Kernel 2: fused adjacency + A@x_last, half-j per block ----------------
// grid (128 i-tiles, 2 halves) x 512 thr (8 waves). Block = 16 rows x 1024
// cols, 8 strips of 128, double-buffered P, ONE barrier per strip (R12's
// proven pattern). Wave w owns col-group w*16..w*16+15 within a strip (S)
// and output-col group w*16..w*16+15 (AX). Partials: 2 per row.
__global__ __launch_bounds__(512, 4) void k2h(
    const unsigned short* __restrict__ emb_bf,
    const unsigned short* __restrict__ xlT_bf,
    const float* __restrict__ sq,
    const float* __restrict__ tempp, const float* __restrict__ thetap,
    float* __restrict__ adjw,      // [2048][2048] f32
    float* __restrict__ outPart,   // [2][2048][128] f32
    float* __restrict__ degPart)   // [2][2048]
{
    constexpr int LDP = 132;
    __shared__ float Pt[2][16 * LDP];
    __shared__ float degS[8][16];

    const int t = threadIdx.x;
    const int lane = t & 63;
    const int w = t >> 6;          // wave 0..7
    const int m = lane & 15;
    const int q = lane >> 4;
    const int i0 = blockIdx.x * 16;
    const int half = blockIdx.y;   // 0/1
    const int jbase = half * 1024;
    const float scale = 1.0f + tempp[0];
    const float bias = 5.0f + thetap[0];

    // A-fragments of emb rows i0..i0+15 (K=64)
    bf16x8 a0 = *(const bf16x8*)(emb_bf + (size_t)(i0 + m) * 64 + q * 8);
    bf16x8 a1 = *(const bf16x8*)(emb_bf + (size_t)(i0 + m) * 64 + 32 + q * 8);
    float sqIr[4];
    #pragma unroll
    for (int r = 0; r < 4; ++r) sqIr[r] = sq[i0 + q * 4 + r];

    f32x4 accO = {0.f, 0.f, 0.f, 0.f};       // out rows q*4+r, col w*16+m
    float dega[4] = {0.f, 0.f, 0.f, 0.f};
    const int cg = w * 16;                    // output col-group (AX)

    for (int jt = 0; jt < 8; ++jt) {
        const int j0 = jbase + jt * 128;
        float* P = &Pt[jt & 1][0];

        // prefetch AX B-fragments (xlT rows cg..cg+15, k = strip cols)
        bf16x8 xb[4];
        #pragma unroll
        for (int s = 0; s < 4; ++s)
            xb[s] = *(const bf16x8*)(xlT_bf + (size_t)(cg + m) * 2048 + j0 + s * 32 + q * 8);

        // S phase: wave w computes strip cols w*16..w*16+15
        {
            const int col = w * 16 + m;
            const int gcol = j0 + col;
            const unsigned short* ebj = emb_bf + (size_t)gcol * 64;
            bf16x8 b0 = *(const bf16x8*)(ebj + q * 8);
            bf16x8 b1 = *(const bf16x8*)(ebj + 32 + q * 8);
            f32x4 S = {0.f, 0.f, 0.f, 0.f};
            S = __builtin_amdgcn_mfma_f32_16x16x32_bf16(a0, b0, S, 0, 0, 0);
            S = __builtin_amdgcn_mfma_f32_16x16x32_bf16(a1, b1, S, 0, 0, 0);

            const float csqJ = sq[gcol];
            #pragma unroll
            for (int r = 0; r < 4; ++r) {
                int grow = i0 + q * 4 + r;
                float dist = 2.0f * S[r] - sqIr[r] - csqJ;
                float z = scale * dist + bias;
                float p = __builtin_amdgcn_rcpf(1.0f + __expf(-z));
                if (grow == gcol) p += 1.0f;
                dega[r] += p;
                P[(q * 4 + r) * LDP + col] = p;
            }
        }
        __syncthreads();

        // adjw store: 512 thr x one f32x4 = 32 lanes x 16B per row-pair ->
        // full 128B lines, 8KB per strip.
        {
            int row = t >> 5;            // 0..15
            int c0 = (t & 31) * 4;       // f32 col 0..124
            f32x4 v = *(const f32x4*)(&P[row * LDP + c0]);
            *(f32x4*)(adjw + (size_t)(i0 + row) * 2048 + j0 + c0) = v;
        }

        // AX: accO += P(16x128) @ xlT(128 x 16-col-group), K=128
        #pragma unroll
        for (int s = 0; s < 4; ++s) {
            float af[8];
            *(f32x4*)(&af[0]) = *(const f32x4*)(&P[m * LDP + s * 32 + q * 8]);
            *(f32x4*)(&af[4]) = *(const f32x4*)(&P[m * LDP + s * 32 + q * 8 + 4]);
            bf16x8 aa = pack_bf8(af);
            accO = __builtin_amdgcn_mfma_f32_16x16x32_bf16(aa, xb[s], accO, 0, 0, 0);
        }
        // next strip's S writes the other P buffer; the barrier at the top of
        // the next iteration orders AX(jt) before S(jt+2) buffer reuse.
    }

    // deg half-partial: reduce over m-lanes, combine 8 waves via LDS
    #pragma unroll
    for (int r = 0; r < 4; ++r) {
        float v = dega[r];
        v += __shfl_xor(v, 1);
        v += __shfl_xor(v, 2);
        v += __shfl_xor(v, 4);
        v += __shfl_xor(v, 8);
        if (m == 0) degS[w][q * 4 + r] = v;
    }
    __syncthreads();
    if (t < 16) {
        float d = 0.f;
        #pragma unroll
        for (int ww = 0; ww < 8; ++ww) d += degS[ww][t];
        degPart[half * 2048 + i0 + t] = d;
    }

    // out half-partial: rows q*4+r, col cg+m (scatter; only 2MB scratch)
    float* op = outPart + (size_t)half * 262144 + (size_t)i0 * 128 + cg + m;
    #pragma unroll
    for (int r = 0; r < 4; ++r)
        op[(size_t)(q * 4 + r) * 128] = accO[r];
}

// ---------------- Kernel 3: out = relu((o0+o1)/(d0+d1)), f32x4 ----------------
__global__ __launch_bounds__(256) void k3_fin(
    const float* __restrict__ outPart, const float* __restrict__ degPart,
    float* __restrict__ out)
{
    int gid = blockIdx.x * 256 + threadIdx.x;   // 65536 = 2048 x 32
    int i = gid >> 5;
    int c0 = (gid & 31) * 4;
    f32x4 v0 = *(const f32x4*)(outPart + (size_t)i * 128 + c0);
    f32x4 v1 = *(const f32x4*)(outPart + 262144 + (size_t)i * 128 + c0);
    float dinv = 1.0f / (degPart[i] + degPart[2048 + i]);
    f32x4 o;
    #pragma unroll
    for (int r = 0; r < 4; ++r) o[r] = fmaxf((v0[r] + v1[r]) * dinv, 0.f);
    *(f32x4*)(out + (size_t)i * 128 + c0) = o;
}

extern "C" void kernel_launch(void* const* d_in, const int* in_sizes, int n_in,
                              void* d_out, int out_size, void* d_ws, size_t ws_size,
                              hipStream_t stream) {
    (void)in_sizes; (void)n_in; (void)out_size; (void)ws_size;
    const float* x     = (const float*)d_in[0];
    const float* W0    = (const float*)d_in[2];
    const float* b0    = (const float*)d_in[3];
    const float* W1    = (const float*)d_in[4];
    const float* b1    = (const float*)d_in[5];
    const float* W2    = (const float*)d_in[6];
    const float* b2    = (const float*)d_in[7];
    const float* temp  = (const float*)d_in[8];
    const float* theta = (const float*)d_in[9];

    char* ws = (char*)d_ws;
    unsigned short* emb_bf = (unsigned short*)(ws);            // ->262144
    unsigned short* xlT_bf = (unsigned short*)(ws + 262144);   // ->786432
    float* sq      = (float*)(ws + 786432);                    // ->794624
    float* degPart = (float*)(ws + 794624);                    // 2x2048x4 ->811008
    float* outPart = (float*)(ws + 811008);                    // 2x2048x128x4 ->2908160
    // total 2.9 MB << proven >=9.25 MB workspace (R14 ran with cnt@9248768)

    float* out  = (float*)d_out;              // [2048*128]
    float* adjw = (float*)d_out + 262144;     // [2048*2048]

    k1_mfma<<<256, 256, 0, stream>>>(x, W0, b0, W1, b1, W2, b2,
                                     emb_bf, xlT_bf, sq);
    k2h<<<dim3(128, 2), 512, 0, stream>>>(emb_bf, xlT_bf, sq, temp, theta,
                                          adjw, outPart, degPart);
    k3_fin<<<256, 256, 0, stream>>>(outPart, degPart, out);
}